// Round 10
// baseline (2989.566 us; speedup 1.0000x reference)
//
#include <hip/hip_runtime.h>
#include <cmath>

#define TOTAL_RAYS (131072 * 16)
#define HDIM 64

typedef float v2f __attribute__((ext_vector_type(2)));
typedef float v4f __attribute__((ext_vector_type(4)));

__device__ unsigned int g_counter;

__global__ void vis_init_counter() { g_counter = 0u; }

// softplus(x) = max(x,0) + log1p(exp(-|x|)).
// Fast form: v_exp_f32 / v_log_f32 (~2-4 ulp absolute). Verified absmax 0 in round 4.
__device__ __forceinline__ float softplus_f(float x) {
    return fmaxf(x, 0.0f) + __logf(1.0f + __expf(-fabsf(x)));
}

extern "C" __global__ void __launch_bounds__(256, 2)   // 128-VGPR budget: acc[32] stays in regs (round-3 regalloc)
vis_trace_kernel(const float* __restrict__ points,
                 const float* __restrict__ cams,
                 const float* __restrict__ W1,
                 const float* __restrict__ b1,
                 const float* __restrict__ W2,
                 const float* __restrict__ b2,
                 const float* __restrict__ W3,
                 const float* __restrict__ b3,
                 int* __restrict__ out)
{
    __shared__ v4f sL1[HDIM];        // {W1x[k], W1y[k], W1z[k], b1[k]}
    __shared__ v4f sW2[HDIM * 16];   // row k contiguous: W2[k][0..63]
    __shared__ v2f sE[HDIM];         // {b2[j], W3[j]}
    __shared__ float sB3;

    const int tid = threadIdx.x;
    if (tid < HDIM) {
        v4f l1 = {W1[tid], W1[HDIM + tid], W1[2 * HDIM + tid], b1[tid]};
        sL1[tid] = l1;
        v2f e = {b2[tid], W3[tid]};
        sE[tid] = e;
    }
    for (int i = tid; i < HDIM * 16; i += 256)
        sW2[i] = reinterpret_cast<const v4f*>(W2)[i];
    if (tid == 0) sB3 = b3[0];
    __syncthreads();

    const int lane = tid & 63;

    bool live = false, maskv = false, mint = false, drained = false;
    float ox = 0.f, oy = 0.f, oz = 0.f, dx = 0.f, dy = 0.f, dz = 0.f;
    float farv = 0.f, dist = 0.f, cur = 0.f, t = 1e-3f;
    int it = 0;
    unsigned int ridx = 0u;

    for (;;) {
        // ---- refill dead lanes from the global ray queue ----
        unsigned long long needm = __ballot(!live);
        if (needm != 0ull && !drained) {
            int cnt = __popcll(needm);
            unsigned int base = 0u;
            if (lane == 0) base = atomicAdd(&g_counter, (unsigned int)cnt);
            base = (unsigned int)__shfl((int)base, 0);
            if (base >= TOTAL_RAYS) drained = true;
            if (!live) {
                unsigned int idx = base + (unsigned int)__popcll(needm & ((1ull << lane) - 1ull));
                if (idx < TOTAL_RAYS) {
                    ridx = idx;
                    const int n = (int)(idx >> 4), c = (int)(idx & 15u);
                    ox = points[3 * n]; oy = points[3 * n + 1]; oz = points[3 * n + 2];
                    const float cx = cams[3 * c], cy = cams[3 * c + 1], cz = cams[3 * c + 2];
                    {
                        #pragma clang fp contract(off)
                        float rx = cx - ox, ry = cy - oy, rz = cz - oz;
                        float nrm = sqrtf(rx * rx + ry * ry + rz * rz);
                        dx = rx / nrm; dy = ry / nrm; dz = rz / nrm;
                        float bq = dx * ox + dy * oy + dz * oz;
                        float oo = ox * ox + oy * oy + oz * oz;
                        float disc = bq * bq - (oo - 1.0f);
                        mint = disc > 0.0f;
                        farv = -bq + sqrtf(fmaxf(disc, 0.0f));
                    }
                    live = true; maskv = true; it = 0;
                    dist = 0.f; cur = 0.f; t = 1e-3f;
                }
            }
        }
        if (__ballot(live) == 0ull) break;

        // ---- one MLP eval at position t (all lanes; !live lanes compute garbage) ----
        float px, py, pz;
        {
            #pragma clang fp contract(off)
            px = ox + t * dx; py = oy + t * dy; pz = oz + t * dz;
        }

        v2f acc[32];
        #pragma unroll
        for (int q = 0; q < 32; ++q) { v2f z = {0.f, 0.f}; acc[q] = z; }

        #pragma unroll 4
        for (int k = 0; k < HDIM; ++k) {
            v4f c1 = sL1[k];
            float a = fmaf(pz, c1.z, fmaf(py, c1.y, px * c1.x)) + c1.w;
            float hk = softplus_f(a);
            v2f hk2 = {hk, hk};
            const v4f* row = &sW2[k * 16];
            #pragma unroll
            for (int q = 0; q < 16; ++q) {
                v4f w = row[q];                               // uniform addr -> LDS broadcast
                v2f w0 = __builtin_shufflevector(w, w, 0, 1);
                v2f w1 = __builtin_shufflevector(w, w, 2, 3);
                acc[2 * q]     = __builtin_elementwise_fma(hk2, w0, acc[2 * q]);     // v_pk_fma_f32
                acc[2 * q + 1] = __builtin_elementwise_fma(hk2, w1, acc[2 * q + 1]);
            }
        }

        float s3 = 0.f;
        #pragma unroll
        for (int q = 0; q < 32; ++q) {
            v2f e0 = sE[2 * q], e1 = sE[2 * q + 1];
            float h2 = softplus_f(acc[q].x + e0.x);
            s3 = fmaf(h2, e0.y, s3);
            float h3 = softplus_f(acc[q].y + e1.x);
            s3 = fmaf(h3, e1.y, s3);
        }
        const float s = s3 + sB3;

        // ---- state update (reference semantics, incl. it==0 init step) ----
        if (live) {
            if (it == 0) {
                cur = s; maskv = (cur >= 0.0f); dist = 1e-3f + cur;
            } else {
                cur = maskv ? s : cur;
                maskv = maskv && (cur >= 5e-7f);
                dist = maskv ? (dist + cur) : dist;
                maskv = maskv && (dist <= farv);
            }
            ++it; t = dist;
            if (!maskv || it >= 32) {       // frozen or all 32 evals done
                out[ridx] = ((dist > farv) && mint) ? 1 : 0;
                live = false;
            }
        }
    }
}

extern "C" void kernel_launch(void* const* d_in, const int* in_sizes, int n_in,
                              void* d_out, int out_size, void* d_ws, size_t ws_size,
                              hipStream_t stream) {
    const float* points = (const float*)d_in[0];
    const float* cams   = (const float*)d_in[1];
    const float* W1     = (const float*)d_in[2];
    const float* b1     = (const float*)d_in[3];
    const float* W2     = (const float*)d_in[4];
    const float* b2     = (const float*)d_in[5];
    const float* W3     = (const float*)d_in[6];
    const float* b3     = (const float*)d_in[7];
    int* out = (int*)d_out;

    hipLaunchKernelGGL(vis_init_counter, dim3(1), dim3(1), 0, stream);
    hipLaunchKernelGGL(vis_trace_kernel, dim3(1024), dim3(256), 0, stream,
                       points, cams, W1, b1, W2, b2, W3, b3, out);
}

// Round 11
// 1771.281 us; speedup vs baseline: 1.6878x; 1.6878x over previous
//
#include <hip/hip_runtime.h>
#include <cmath>

#define TOTAL_RAYS (131072 * 16)
#define HDIM 64

typedef float v2f __attribute__((ext_vector_type(2)));
typedef float v4f __attribute__((ext_vector_type(4)));

__device__ unsigned int g_counter;

__global__ void vis_init_counter() { g_counter = 0u; }

// softplus(x) = max(x,0) + log1p(exp(-|x|)).
// Fast form: v_exp_f32 / v_log_f32 (~2-4 ulp absolute). Verified absmax 0 since round 4.
__device__ __forceinline__ float softplus_f(float x) {
    return fmaxf(x, 0.0f) + __logf(1.0f + __expf(-fabsf(x)));
}

// Weights are read DIRECTLY from global with wave-uniform addresses:
// uniform loop index + __restrict__ const pointers -> compiler emits s_load
// (scalar cache broadcast, SGPR operand in v_pk_fma). This takes the 1088
// ds_read_b128/eval off the LDS pipe, which has no broadcast compression
// (wave64 b128 = 1024B through 256B/clk crossbar even at uniform address,
// and 4 SIMDs share 1 LDS unit -> was ~4x oversubscribed, VALUBusy 33%).
extern "C" __global__ void __launch_bounds__(256, 2)   // 128-VGPR budget: acc[32] stays in regs
vis_trace_kernel(const float* __restrict__ points,
                 const float* __restrict__ cams,
                 const float* __restrict__ W1,
                 const float* __restrict__ b1,
                 const float* __restrict__ W2,
                 const float* __restrict__ b2,
                 const float* __restrict__ W3,
                 const float* __restrict__ b3,
                 int* __restrict__ out)
{
    const v4f* __restrict__ W2v = reinterpret_cast<const v4f*>(W2);  // row k = W2v[k*16 .. k*16+15]
    const float sB3 = b3[0];                                          // uniform -> SGPR, hoisted

    const int lane = threadIdx.x & 63;

    bool live = false, maskv = false, mint = false, drained = false;
    float ox = 0.f, oy = 0.f, oz = 0.f, dx = 0.f, dy = 0.f, dz = 0.f;
    float farv = 0.f, dist = 0.f, cur = 0.f, t = 1e-3f;
    int it = 0;
    unsigned int ridx = 0u;

    for (;;) {
        // ---- refill dead lanes from the global ray queue ----
        unsigned long long needm = __ballot(!live);
        if (needm != 0ull && !drained) {
            int cnt = __popcll(needm);
            unsigned int base = 0u;
            if (lane == 0) base = atomicAdd(&g_counter, (unsigned int)cnt);
            base = (unsigned int)__shfl((int)base, 0);
            if (base >= TOTAL_RAYS) drained = true;
            if (!live) {
                unsigned int idx = base + (unsigned int)__popcll(needm & ((1ull << lane) - 1ull));
                if (idx < TOTAL_RAYS) {
                    ridx = idx;
                    const int n = (int)(idx >> 4), c = (int)(idx & 15u);
                    ox = points[3 * n]; oy = points[3 * n + 1]; oz = points[3 * n + 2];
                    const float cx = cams[3 * c], cy = cams[3 * c + 1], cz = cams[3 * c + 2];
                    {
                        #pragma clang fp contract(off)
                        float rx = cx - ox, ry = cy - oy, rz = cz - oz;
                        float nrm = sqrtf(rx * rx + ry * ry + rz * rz);
                        dx = rx / nrm; dy = ry / nrm; dz = rz / nrm;
                        float bq = dx * ox + dy * oy + dz * oz;
                        float oo = ox * ox + oy * oy + oz * oz;
                        float disc = bq * bq - (oo - 1.0f);
                        mint = disc > 0.0f;
                        farv = -bq + sqrtf(fmaxf(disc, 0.0f));
                    }
                    live = true; maskv = true; it = 0;
                    dist = 0.f; cur = 0.f; t = 1e-3f;
                }
            }
        }
        if (__ballot(live) == 0ull) break;

        // ---- one MLP eval at position t (all lanes; !live lanes compute garbage) ----
        float px, py, pz;
        {
            #pragma clang fp contract(off)
            px = ox + t * dx; py = oy + t * dy; pz = oz + t * dz;
        }

        v2f acc[32];
        #pragma unroll
        for (int q = 0; q < 32; ++q) { v2f z = {0.f, 0.f}; acc[q] = z; }

        #pragma unroll 2
        for (int k = 0; k < HDIM; ++k) {
            // W1 columns + b1: uniform scalar loads (adjacent k merge into s_load_dwordx2)
            float a = fmaf(pz, W1[2 * HDIM + k],
                      fmaf(py, W1[HDIM + k],
                           px * W1[k])) + b1[k];
            float hk = softplus_f(a);
            v2f hk2 = {hk, hk};
            const v4f* row = &W2v[k * 16];
            #pragma unroll
            for (int q = 0; q < 16; ++q) {
                v4f w = row[q];                               // uniform addr -> s_load, SGPR broadcast
                v2f w0 = __builtin_shufflevector(w, w, 0, 1);
                v2f w1 = __builtin_shufflevector(w, w, 2, 3);
                acc[2 * q]     = __builtin_elementwise_fma(hk2, w0, acc[2 * q]);     // v_pk_fma_f32
                acc[2 * q + 1] = __builtin_elementwise_fma(hk2, w1, acc[2 * q + 1]);
            }
        }

        float s3 = 0.f;
        #pragma unroll
        for (int q = 0; q < 32; ++q) {
            float h2 = softplus_f(acc[q].x + b2[2 * q]);
            s3 = fmaf(h2, W3[2 * q], s3);
            float h3 = softplus_f(acc[q].y + b2[2 * q + 1]);
            s3 = fmaf(h3, W3[2 * q + 1], s3);
        }
        const float s = s3 + sB3;

        // ---- state update (reference semantics, incl. it==0 init step) ----
        if (live) {
            if (it == 0) {
                cur = s; maskv = (cur >= 0.0f); dist = 1e-3f + cur;
            } else {
                cur = maskv ? s : cur;
                maskv = maskv && (cur >= 5e-7f);
                dist = maskv ? (dist + cur) : dist;
                maskv = maskv && (dist <= farv);
            }
            ++it; t = dist;
            if (!maskv || it >= 32) {       // frozen or all 32 evals done
                out[ridx] = ((dist > farv) && mint) ? 1 : 0;
                live = false;
            }
        }
    }
}

extern "C" void kernel_launch(void* const* d_in, const int* in_sizes, int n_in,
                              void* d_out, int out_size, void* d_ws, size_t ws_size,
                              hipStream_t stream) {
    const float* points = (const float*)d_in[0];
    const float* cams   = (const float*)d_in[1];
    const float* W1     = (const float*)d_in[2];
    const float* b1     = (const float*)d_in[3];
    const float* W2     = (const float*)d_in[4];
    const float* b2     = (const float*)d_in[5];
    const float* W3     = (const float*)d_in[6];
    const float* b3     = (const float*)d_in[7];
    int* out = (int*)d_out;

    hipLaunchKernelGGL(vis_init_counter, dim3(1), dim3(1), 0, stream);
    hipLaunchKernelGGL(vis_trace_kernel, dim3(1024), dim3(256), 0, stream,
                       points, cams, W1, b1, W2, b2, W3, b3, out);
}